// Round 9
// baseline (159.324 us; speedup 1.0000x reference)
//
#include <hip/hip_runtime.h>
#include <hip/hip_bf16.h>

#define BATCH   16384
#define NSTEPS  100
#define DT_     0.01f
#define SQRTDT  0.1f
#define SIGMA0_ 0.5f

typedef _Float16  f16x2  __attribute__((ext_vector_type(2)));
typedef _Float16  f16x4  __attribute__((ext_vector_type(4)));
typedef _Float16  f16x8  __attribute__((ext_vector_type(8)));
typedef __fp16    h16x2  __attribute__((ext_vector_type(2)));
typedef float     f32x4  __attribute__((ext_vector_type(4)));

__global__ void zero_out_kernel(float* out) { if (threadIdx.x == 0) out[0] = 0.0f; }

static __device__ __forceinline__ f16x4 pk4(const f32x4& d) {
    union { h16x2 h[2]; f16x4 v; } c;
    c.h[0] = __builtin_amdgcn_cvt_pkrtz(d[0], d[1]);
    c.h[1] = __builtin_amdgcn_cvt_pkrtz(d[2], d[3]);
    return c.v;
}

struct N3 { float a, b, c; };

// R9: register-direct noise (memory-path probe). R8 autopsy: ~1100 cy/step
// with BOTH waves stalled; suspect = global_load_lds fills + per-step LDS
// round trips behind manual vmcnt builtins. This round DELETES that path:
// noise is loaded per-lane into named register slots 8 steps ahead (plain
// global_load_dword, compiler-scheduled waits, no manual vmcnt, no LDS
// rings). Everything else identical to R8 (z/q decoupled split, role-flip
// mixing, setprio(1) on q, t-table in LDS, full-depth y-ring, flag/4).
__launch_bounds__(256, 2)
__global__ void deepbsde_kernel(
    const float* __restrict__ y0,  const float* __restrict__ Y0,
    const float* __restrict__ zW1, const float* __restrict__ zb1,
    const float* __restrict__ zW2, const float* __restrict__ zb2,
    const float* __restrict__ zW3, const float* __restrict__ zb3,
    const float* __restrict__ qW1, const float* __restrict__ qb1,
    const float* __restrict__ qW2, const float* __restrict__ qb2,
    const float* __restrict__ qW3, const float* __restrict__ qb3,
    const float* __restrict__ dW,  const float* __restrict__ dZ,
    float* __restrict__ out)
{
    __shared__ __align__(16) _Float16 tbl[NSTEPS * 128];  // [step][q4][16 f16x2]
    __shared__ float yring[2][NSTEPS + 1][16];            // full-depth y history
    __shared__ float ffin[2][16];                         // q-wave Facc finals
    __shared__ int   flags[2][2];                         // [g][0]=q progress flag

    const int tid  = threadIdx.x;
    const int lane = tid & 63;
    const int w    = tid >> 6;        // 0..3
    const int g    = w >> 1;          // waves 0,1 -> group 0; 2,3 -> group 1
    const int flip = (((int)blockIdx.x >> 3) ^ ((int)blockIdx.x >> 8)) & 1;
    const bool isQ = ((w & 1) ^ flip) != 0;
    const int ln15 = lane & 15, q4 = lane >> 4;
    const int gw   = (blockIdx.x << 1) + g;
    const int pbase = gw << 4;        // 16 paths per group

    if (tid < 4) ((int*)flags)[tid] = 0;

    // ---- one-time t-table (both MLP halves), identical arithmetic ----
    {
        float tt = 0.0f;
        for (int i = 0; i < NSTEPS; ++i) {
            int r = (tid - (i << 6)) & 255;
            if (r < 64) {
                int q4e = r >> 4, mlp_ = (r >> 3) & 1, m = r & 7;
                const float* Wp = mlp_ ? qW1 : zW1;
                const float* bp = mlp_ ? qb1 : zb1;
                int i0 = 2*m, i1 = 2*m + 1;
                int k0 = 32*(i0 >> 3) + 8*q4e + (i0 & 7);
                int k1 = 32*(i1 >> 3) + 8*q4e + (i1 & 7);
                _Float16 th = (_Float16)tt;
                f16x2 A = {(_Float16)Wp[k0], (_Float16)Wp[k1]};
                f16x2 C = {(_Float16)bp[k0], (_Float16)bp[k1]};
                f16x2 tv = {th, th};
                f16x2 v = A*tv + C;
                int idx = (i*4 + q4e)*16 + mlp_*8 + m;
                *(f16x2*)&tbl[idx << 1] = v;
            }
            tt += DT_;
        }
    }

    // ---- role-selected weights ----
    const float* W1p = isQ ? qW1 : zW1;
    const float* W2p = isQ ? qW2 : zW2;
    const float* b2p = isQ ? qb2 : zb2;

    f16x2 B1[8];
#pragma unroll
    for (int m = 0; m < 8; ++m) {
        int i0 = 2*m, i1 = 2*m + 1;
        int k0 = 32*(i0 >> 3) + 8*q4 + (i0 & 7);
        int k1 = 32*(i1 >> 3) + 8*q4 + (i1 & 7);
        B1[m] = (f16x2){(_Float16)W1p[64 + k0], (_Float16)W1p[64 + k1]};
    }

    f16x8 Af[4][2];
#pragma unroll
    for (int tN = 0; tN < 4; ++tN)
#pragma unroll
        for (int f = 0; f < 2; ++f)
#pragma unroll
            for (int j = 0; j < 8; ++j) {
                int k = 32*f + 8*q4 + j, n = 16*tN + ln15;
                Af[tN][f][j] = (_Float16)W2p[k*64 + n];
            }

    f32x4 b2v[4];
#pragma unroll
    for (int tN = 0; tN < 4; ++tN)
#pragma unroll
        for (int r = 0; r < 4; ++r)
            b2v[tN][r] = b2p[16*tN + 4*q4 + r];

    const int c3 = ln15 & 3;
    f16x8 A3[2];
#pragma unroll
    for (int fl = 0; fl < 2; ++fl)
#pragma unroll
        for (int j = 0; j < 8; ++j) {
            int tN = 2*fl + (j >> 2);
            int n  = 16*tN + 4*q4 + (j & 3);
            float wv = isQ ? ((c3 == 3) ? qW3[n]                 : 0.0f)
                           : ((c3 < 3)  ? SQRTDT * zW3[n*3 + c3] : 0.0f);
            A3[fl][j] = (_Float16)wv;
        }

    const f32x4 C3b = isQ ? (f32x4){0.0f, 0.0f, 0.0f, qb3[0]}
                          : (f32x4){SQRTDT*zb3[0], SQRTDT*zb3[1], SQRTDT*zb3[2], 0.0f};

    const float CSIG = SIGMA0_ * SQRTDT;
    const float NHDT = -0.5f * DT_;
    const float y0v = y0[0], Y0v = Y0[0];

    const f16x2 zero2h = {(_Float16)0.0f, (_Float16)0.0f};
    const f16x4 zero4h = {(_Float16)0.0f, (_Float16)0.0f, (_Float16)0.0f, (_Float16)0.0f};

    // seed y(0) so z batches are uniform
    if (isQ && q4 == 0) *(volatile float*)&yring[g][0][ln15] = y0v;

    __syncthreads();   // table + flags + y0 visible; ONLY block-wide sync

    // register-direct noise loaders (per-lane, path = pbase + ln15)
    auto loadW = [&](int i, N3& d) {
        int ic = (i < NSTEPS) ? i : NSTEPS - 1;
        const float* p = dW + ((size_t)ic * BATCH + pbase + ln15) * 3;
        d.a = p[0]; d.b = p[1]; d.c = p[2];
    };
    auto loadZ = [&](int i, N3& d) {
        int ic = (i < NSTEPS) ? i : NSTEPS - 1;
        const float* p = dZ + ((size_t)ic * BATCH + pbase + ln15) * 3;
        d.a = p[0]; d.b = p[1]; d.c = p[2];
    };

    if (!isQ) {
        // ========== z-wave: independent steps, pair-interleaved ==========
        float Ysum = 0.0f, acc = 0.0f;
        float ya, yb, yc, yd;

        auto ybatch = [&](int base) {  // reads y(base..base+3); needs flag >= base+4
            volatile int* qf = &flags[g][0];
            while (*qf < base + 4) { }
            ya = *(volatile float*)&yring[g][base + 0][ln15];
            yb = *(volatile float*)&yring[g][base + 1][ln15];
            yc = *(volatile float*)&yring[g][base + 2][ln15];
            yd = *(volatile float*)&yring[g][base + 3][ln15];
        };

        auto zpair = [&](int iA, float yA, int iB, float yB,
                         const N3& wA, const N3& zA, const N3& wB, const N3& zB) {
            const f16x8* tpA = (const f16x8*)(tbl + (iA*4 + q4)*32);
            const f16x8* tpB = (const f16x8*)(tbl + (iB*4 + q4)*32);
            union U8 { f16x8 v; f16x2 h[4]; };
            U8 TA0; TA0.v = tpA[0]; U8 TA1; TA1.v = tpA[1];
            U8 TB0; TB0.v = tpB[0]; U8 TB1; TB1.v = tpB[1];

            _Float16 yhA = (_Float16)yA, yhB = (_Float16)yB;
            const f16x2 yvA = {yhA, yhA}, yvB = {yhB, yhB};
            union { f16x2 h[4]; f16x8 v; } a0, a1, b0, b1;
#pragma unroll
            for (int m = 0; m < 4; ++m) {
                a0.h[m] = __builtin_elementwise_max((f16x2)(B1[m]*yvA   + TA0.h[m]), zero2h);
                b0.h[m] = __builtin_elementwise_max((f16x2)(B1[m]*yvB   + TB0.h[m]), zero2h);
                a1.h[m] = __builtin_elementwise_max((f16x2)(B1[m+4]*yvA + TA1.h[m]), zero2h);
                b1.h[m] = __builtin_elementwise_max((f16x2)(B1[m+4]*yvB + TB1.h[m]), zero2h);
            }

            union { f16x4 q[4]; f16x8 o[2]; } BA, BB;
#pragma unroll
            for (int tN = 0; tN < 4; ++tN) {
                f32x4 dA = b2v[tN];
                f32x4 dB = b2v[tN];
                dA = __builtin_amdgcn_mfma_f32_16x16x32_f16(Af[tN][0], a0.v, dA, 0, 0, 0);
                dB = __builtin_amdgcn_mfma_f32_16x16x32_f16(Af[tN][0], b0.v, dB, 0, 0, 0);
                dA = __builtin_amdgcn_mfma_f32_16x16x32_f16(Af[tN][1], a1.v, dA, 0, 0, 0);
                dB = __builtin_amdgcn_mfma_f32_16x16x32_f16(Af[tN][1], b1.v, dB, 0, 0, 0);
                BA.q[tN] = __builtin_elementwise_max(pk4(dA), zero4h);
                BB.q[tN] = __builtin_elementwise_max(pk4(dB), zero4h);
            }

            f32x4 PA = C3b, PB = C3b;
            PA = __builtin_amdgcn_mfma_f32_16x16x32_f16(A3[0], BA.o[0], PA, 0, 0, 0);
            PB = __builtin_amdgcn_mfma_f32_16x16x32_f16(A3[0], BB.o[0], PB, 0, 0, 0);
            PA = __builtin_amdgcn_mfma_f32_16x16x32_f16(A3[1], BA.o[1], PA, 0, 0, 0);
            PB = __builtin_amdgcn_mfma_f32_16x16x32_f16(A3[1], BB.o[1], PB, 0, 0, 0);

            float zdwA = fmaf(PA[2], wA.c, fmaf(PA[1], wA.b, PA[0]*wA.a));
            float zdzA = fmaf(PA[2], zA.c, fmaf(PA[1], zA.b, PA[0]*zA.a));
            Ysum += zdwA;
            float rA = zdwA - zdzA;
            acc = fmaf(rA, rA, acc);
            float zdwB = fmaf(PB[2], wB.c, fmaf(PB[1], wB.b, PB[0]*wB.a));
            float zdzB = fmaf(PB[2], zB.c, fmaf(PB[1], zB.b, PB[0]*zB.a));
            Ysum += zdwB;
            float rB = zdwB - zdzB;
            acc = fmaf(rB, rB, acc);
        };

        // 8-deep register noise ring (named slots, static use)
        N3 w0,w1,w2,w3,w4,w5,w6,w7, z0,z1,z2,z3,z4,z5,z6,z7;
        loadW(0,w0); loadZ(0,z0); loadW(1,w1); loadZ(1,z1);
        loadW(2,w2); loadZ(2,z2); loadW(3,w3); loadZ(3,z3);
        loadW(4,w4); loadZ(4,z4); loadW(5,w5); loadZ(5,z5);
        loadW(6,w6); loadZ(6,z6); loadW(7,w7); loadZ(7,z7);

#pragma unroll 1
        for (int k = 0; k < 12; ++k) {
            int i = 8*k;
            ybatch(i);
            zpair(i,     ya, i + 1, yb, w0, z0, w1, z1);
            loadW(i + 8,  w0); loadZ(i + 8,  z0);
            loadW(i + 9,  w1); loadZ(i + 9,  z1);
            zpair(i + 2, yc, i + 3, yd, w2, z2, w3, z3);
            loadW(i + 10, w2); loadZ(i + 10, z2);
            loadW(i + 11, w3); loadZ(i + 11, z3);
            ybatch(i + 4);
            zpair(i + 4, ya, i + 5, yb, w4, z4, w5, z5);
            loadW(i + 12, w4); loadZ(i + 12, z4);
            loadW(i + 13, w5); loadZ(i + 13, z5);
            zpair(i + 6, yc, i + 7, yd, w6, z6, w7, z7);
            loadW(i + 14, w6); loadZ(i + 14, z6);
            loadW(i + 15, w7); loadZ(i + 15, z7);
        }
        // tail: steps 96..99 in slots 0..3
        ybatch(96);
        zpair(96, ya, 97, yb, w0, z0, w1, z1);
        zpair(98, yc, 99, yd, w2, z2, w3, z3);

        // terminal: wait for q finals (flag = NSTEPS+1)
        {
            volatile int* qf = &flags[g][0];
            while (*qf < NSTEPS + 1) { }
        }
        float Fq = *(volatile float*)&ffin[g][ln15];
        float yT = *(volatile float*)&yring[g][NSTEPS][ln15];
        float Yvf = Y0v + Fq + Ysum;
        float dterm = Yvf - yT*yT;
        acc = fmaf(dterm, dterm, acc);

        float val = (q4 == 0) ? acc : 0.0f;
#pragma unroll
        for (int off = 1; off < 64; off <<= 1) val += __shfl_xor(val, off);
        if (lane == 0) atomicAdd(out, val * (1.0f / BATCH));
    } else {
        // ========== q-wave: serial y-recurrence, issue-priority boosted ==========
        __builtin_amdgcn_s_setprio(1);
        float y = y0v, Facc = 0.0f;
        f16x8 c0, c1, d0, d1;
        { const f16x8* tp = (const f16x8*)(tbl + q4*32); c0 = tp[2]; c1 = tp[3]; }

        auto qbody = [&](int j, const N3& nw, f16x8& t0, f16x8& t1, f16x8& u0, f16x8& u1) {
            int jp = j + 1; jp = (jp > NSTEPS - 1) ? NSTEPS - 1 : jp;
            { const f16x8* tp = (const f16x8*)(tbl + (jp*4 + q4)*32); u0 = tp[2]; u1 = tp[3]; }

            _Float16 yh = (_Float16)y;
            const f16x2 yv = {yh, yh};
            union U8 { f16x8 v; f16x2 h[4]; };
            U8 T0; T0.v = t0; U8 T1; T1.v = t1;
            union { f16x2 h[4]; f16x8 v; } b0, b1;
#pragma unroll
            for (int m = 0; m < 4; ++m) {
                b0.h[m] = __builtin_elementwise_max((f16x2)(B1[m]*yv   + T0.h[m]), zero2h);
                b1.h[m] = __builtin_elementwise_max((f16x2)(B1[m+4]*yv + T1.h[m]), zero2h);
            }
            union { f16x4 q[4]; f16x8 o[2]; } Bh;
#pragma unroll
            for (int tN = 0; tN < 4; ++tN) {
                f32x4 d = b2v[tN];
                d = __builtin_amdgcn_mfma_f32_16x16x32_f16(Af[tN][0], b0.v, d, 0, 0, 0);
                d = __builtin_amdgcn_mfma_f32_16x16x32_f16(Af[tN][1], b1.v, d, 0, 0, 0);
                Bh.q[tN] = __builtin_elementwise_max(pk4(d), zero4h);
            }
            f32x4 Pv = C3b;
            Pv = __builtin_amdgcn_mfma_f32_16x16x32_f16(A3[0], Bh.o[0], Pv, 0, 0, 0);
            Pv = __builtin_amdgcn_mfma_f32_16x16x32_f16(A3[1], Bh.o[1], Pv, 0, 0, 0);

            float qv = Pv[3];
            float snw = (nw.a + nw.b) + nw.c;
            Facc = fmaf(NHDT*qv, qv, Facc);
            y = fmaf(CSIG, snw, fmaf(qv, DT_, y));
            if (q4 == 0) *(volatile float*)&yring[g][j + 1][ln15] = y;  // bare ds_write
        };

        // 8-deep register noise ring (dW only)
        N3 n0,n1,n2,n3,n4,n5,n6,n7;
        loadW(0,n0); loadW(1,n1); loadW(2,n2); loadW(3,n3);
        loadW(4,n4); loadW(5,n5); loadW(6,n6); loadW(7,n7);

#pragma unroll 1
        for (int k = 0; k < 12; ++k) {
            int j = 8*k;
            qbody(j,     n0, c0, c1, d0, d1);  loadW(j + 8,  n0);
            qbody(j + 1, n1, d0, d1, c0, c1);  loadW(j + 9,  n1);
            qbody(j + 2, n2, c0, c1, d0, d1);  loadW(j + 10, n2);
            qbody(j + 3, n3, d0, d1, c0, c1);  loadW(j + 11, n3);
            __builtin_amdgcn_s_waitcnt(0xC07F);                 // lgkmcnt(0): y writes landed
            if (lane == 0) *(volatile int*)&flags[g][0] = j + 4;
            qbody(j + 4, n4, c0, c1, d0, d1);  loadW(j + 12, n4);
            qbody(j + 5, n5, d0, d1, c0, c1);  loadW(j + 13, n5);
            qbody(j + 6, n6, c0, c1, d0, d1);  loadW(j + 14, n6);
            qbody(j + 7, n7, d0, d1, c0, c1);  loadW(j + 15, n7);
            __builtin_amdgcn_s_waitcnt(0xC07F);
            if (lane == 0) *(volatile int*)&flags[g][0] = j + 8;
        }
        // tail: steps 96..99 in slots 0..3
        qbody(96, n0, c0, c1, d0, d1);
        qbody(97, n1, d0, d1, c0, c1);
        qbody(98, n2, c0, c1, d0, d1);
        qbody(99, n3, d0, d1, c0, c1);
        __builtin_amdgcn_s_waitcnt(0xC07F);                     // y(100) landed
        if (lane == 0) *(volatile int*)&flags[g][0] = NSTEPS;

        if (q4 == 0) *(volatile float*)&ffin[g][ln15] = Facc;
        __builtin_amdgcn_s_waitcnt(0xC07F);
        if (lane == 0) *(volatile int*)&flags[g][0] = NSTEPS + 1;
    }
}

extern "C" void kernel_launch(void* const* d_in, const int* in_sizes, int n_in,
                              void* d_out, int out_size, void* d_ws, size_t ws_size,
                              hipStream_t stream)
{
    zero_out_kernel<<<1, 64, 0, stream>>>((float*)d_out);
    deepbsde_kernel<<<512, 256, 0, stream>>>(
        (const float*)d_in[0],  (const float*)d_in[1],
        (const float*)d_in[2],  (const float*)d_in[3],
        (const float*)d_in[4],  (const float*)d_in[5],
        (const float*)d_in[6],  (const float*)d_in[7],
        (const float*)d_in[8],  (const float*)d_in[9],
        (const float*)d_in[10], (const float*)d_in[11],
        (const float*)d_in[12], (const float*)d_in[13],
        (const float*)d_in[14], (const float*)d_in[15],
        (float*)d_out);
}